// Round 8
// baseline (126.700 us; speedup 1.0000x reference)
//
#include <hip/hip_runtime.h>
#include <math.h>

#define D 128
#define B 8
#define T_SAMP 32768
#define K 512
#define NT 8
#define NFRM 128

// ws float-region layout
#define WS_C1   0
#define WS_ENV8 1024
#define WS_SEL  2048
#define WS_VAL  6144
#define WS_B3P  6160
// bf16 transposed-weight region (byte offset; element offsets below)
#define WSBF_BYTE 32768
#define OP1 0        // pw1T [128][72]
#define OP2 9216     // pw2T [128][136]
#define OP3 26624    // pw3T
#define OS1 44032    // skw1T
#define OS2 61440    // skw2T
#define OS3 78848    // skw3T [512][136]
#define WTOT 148480
#define WS_NEED (WSBF_BYTE + WTOT*2)

typedef __attribute__((ext_vector_type(8))) short short8;
typedef __attribute__((ext_vector_type(4))) float f32x4;

#define LOG2E 1.4426950408889634f

__device__ __forceinline__ float lrelu(float v){ return fmaxf(v, 0.2f*v); }

__device__ __forceinline__ unsigned cvtpk(float lo, float hi){
    unsigned r;
    asm("v_cvt_pk_bf16_f32 %0, %1, %2" : "=v"(r) : "v"(lo), "v"(hi));
    return r;
}
__device__ __forceinline__ unsigned short bfr(float f){
    unsigned u = __builtin_bit_cast(unsigned, f); u += 0x7fffu + ((u>>16)&1u);
    return (unsigned short)(u>>16);
}
__device__ __forceinline__ float bf2f(short s){
    unsigned u = ((unsigned)(unsigned short)s) << 16;
    return __builtin_bit_cast(float, u);
}
__device__ __forceinline__ float exp2fast(float x){
#if __has_builtin(__builtin_amdgcn_exp2f)
    return __builtin_amdgcn_exp2f(x);
#else
    return __expf(x*0.6931471805599453f);
#endif
}
__device__ __forceinline__ float sin_rev(float fr){
#if __has_builtin(__builtin_amdgcn_sinf)
    return __builtin_amdgcn_sinf(fr);
#else
    return __sinf(fr*6.283185307179586f);
#endif
}
__device__ __forceinline__ float cos_rev(float fr){
#if __has_builtin(__builtin_amdgcn_cosf)
    return __builtin_amdgcn_cosf(fr);
#else
    return __cosf(fr*6.283185307179586f);
#endif
}
// pe value for column j (0=raw pos, 1..16 sin, 17..32 cos, else 0)
__device__ __forceinline__ float pe_val(float pf, int j){
    if (j == 0) return pf;
    if (j > 32) return 0.f;
    const bool is_sin = (j <= 16);
    int e = is_sin ? (j + 125) : (j + 109);     // 2^(j-2) or 2^(j-18): revolutions scale
    float sc = __builtin_bit_cast(float, ((unsigned)e) << 23);
    float u = pf * sc;
    float fr = u - floorf(u);
    return is_sin ? sin_rev(fr) : cos_rev(fr);
}

#define VMCNT0 asm volatile("s_waitcnt vmcnt(0)" ::: "memory")

// ---------------- prep helper (fp32, tiny) ----------------
__device__ void layer128(const float* __restrict__ in, const float* __restrict__ w,
                         const float* __restrict__ bias, float* __restrict__ outp,
                         int tid, int mode)
{
    int n = tid & 127, bg = tid >> 7;
    const float* i0 = in + (bg*4+0)*D;
    const float* i1 = in + (bg*4+1)*D;
    const float* i2 = in + (bg*4+2)*D;
    const float* i3 = in + (bg*4+3)*D;
    float bb = bias[n];
    float a0=bb,a1=bb,a2=bb,a3=bb;
    for (int j=0;j<D;j++){
        float wv = w[j*D+n];
        a0 = fmaf(i0[j], wv, a0);
        a1 = fmaf(i1[j], wv, a1);
        a2 = fmaf(i2[j], wv, a2);
        a3 = fmaf(i3[j], wv, a3);
    }
    if (mode==0){ a0=lrelu(a0);a1=lrelu(a1);a2=lrelu(a2);a3=lrelu(a3); }
    else if (mode==1){ a0=fabsf(a0);a1=fabsf(a1);a2=fabsf(a2);a3=fabsf(a3); }
    outp[(bg*4+0)*D+n]=a0;
    outp[(bg*4+1)*D+n]=a1;
    outp[(bg*4+2)*D+n]=a2;
    outp[(bg*4+3)*D+n]=a3;
}

// block 0: prep (c1/env/sel/values/b3p). blocks 1..: transpose weights to bf16 k-contig padded.
__global__ __launch_bounds__(256) void setup_kernel(
    const float* __restrict__ x, const float* __restrict__ wt,
    const float* __restrict__ tc_w1, const float* __restrict__ tc_b1,
    const float* __restrict__ tc_w2, const float* __restrict__ tc_b2,
    const float* __restrict__ tc_w3, const float* __restrict__ tc_b3,
    const float* __restrict__ env_w1, const float* __restrict__ env_b1,
    const float* __restrict__ env_w2, const float* __restrict__ env_b2,
    const float* __restrict__ env_w3, const float* __restrict__ env_b3,
    const float* __restrict__ sk_w1, const float* __restrict__ sk_b1,
    const float* __restrict__ pos_w1, const float* __restrict__ pos_w2,
    const float* __restrict__ pos_w3, const float* __restrict__ sk_w2,
    const float* __restrict__ sk_w3, const float* __restrict__ sk_b3,
    float* __restrict__ ws)
{
    __shared__ float xl[B*D], buf1[B*D], buf2[B*D];
    __shared__ float lgts[B*NT], pmax[NT*8], mxr[NT];
    __shared__ int idxl[B];
    int tid = threadIdx.x;

    if (blockIdx.x != 0){
        int idx = (blockIdx.x - 1)*256 + tid;
        if (idx >= WTOT) return;
        unsigned short* wb = (unsigned short*)((char*)ws + WSBF_BYTE);
        float v;
        if (idx < OP2){
            int n = idx/72, k = idx%72;
            v = (k < 33) ? pos_w1[k*D + n] : 0.f;
        } else if (idx < OS3){
            int r = idx - OP2; int wsel = r/17408; int i = r%17408;
            int n = i/136, k = i%136;
            const float* W = wsel==0?pos_w2: wsel==1?pos_w3: wsel==2? sk_w1 : sk_w2;
            v = (k < 128) ? W[k*D + n] : 0.f;
        } else {
            int i = idx - OS3; int n = i/136, k = i%136;
            v = (k < 128) ? sk_w3[k*K + n] : 0.f;
        }
        wb[idx] = bfr(v);
        return;
    }

    for (int i=tid;i<B*D;i+=256) xl[i]=x[i];
    for (int i=tid;i<K;i+=256) ws[WS_B3P+i] = sk_b3[i]*LOG2E;
    __syncthreads();
    layer128(xl, tc_w1, tc_b1, buf1, tid, 0);
    __syncthreads();
    layer128(buf1, tc_w2, tc_b2, buf2, tid, 0);
    __syncthreads();
    if (tid < 64){
        int b = tid>>3, n = tid&7;
        float a = tc_b3[n];
        for (int j=0;j<D;j++) a = fmaf(buf2[b*D+j], tc_w3[j*NT+n], a);
        lgts[b*NT+n] = a;
    } else if (tid < 128){
        int r = (tid-64)>>3, p = tid&7;
        float m = -1e30f;
        for (int k=p*64;k<p*64+64;k++) m = fmaxf(m, wt[r*K+k]);
        pmax[r*8+p] = m;
    }
    __syncthreads();
    if (tid < 8){
        int b = tid; float m = -1e30f; int idx = 0;
        for (int n=0;n<NT;n++){ float v = lgts[b*NT+n]; if (v > m){ m=v; idx=n; } }
        float S = 0.f;
        for (int n=0;n<NT;n++) S += expf(lgts[b*NT+n]-m);
        ws[WS_VAL+b] = 1.0f/S;
        idxl[b] = idx;
    } else if (tid < 16){
        int r = tid-8; float m = -1e30f;
        for (int p=0;p<8;p++) m = fmaxf(m, pmax[r*8+p]);
        mxr[r] = m;
    }
    __syncthreads();
    for (int o=tid;o<B*K;o+=256){
        int b = o>>9, k = o&(K-1);
        int id = idxl[b];
        ws[WS_SEL+o] = wt[id*K+k] / (mxr[id] + 1e-8f);
    }
    layer128(xl, env_w1, env_b1, buf1, tid, 0);
    __syncthreads();
    layer128(buf1, env_w2, env_b2, buf2, tid, 0);
    __syncthreads();
    layer128(buf2, env_w3, env_b3, ws+WS_ENV8, tid, 1);
    layer128(xl, sk_w1, sk_b1, ws+WS_C1, tid, 2);
}

// swapped small layer: A-frags from GLOBAL transposed weights; B-frags from LDS; out to LDS.
template<int NKT, int KSTR, bool ACT>
__device__ __forceinline__ void layerGg(const unsigned short* __restrict__ Wg,
                                        const unsigned char* inb, unsigned char* outb,
                                        const float* biasp, int wv, int lg, int lc)
{
    const f32x4 z = {0.f,0.f,0.f,0.f};
    short8 aw[NKT];
    #pragma unroll
    for (int kt=0;kt<NKT;kt++)
        aw[kt] = *(const short8*)(Wg + (16*wv+lc)*KSTR + 32*kt + 8*lg);
    f32x4 bb = z;
    if (biasp) bb = *(const f32x4*)(biasp + 16*wv + 4*lg);
    #pragma unroll
    for (int rt=0;rt<2;rt++){
        f32x4 d = z;
        #pragma unroll
        for (int kt=0;kt<NKT;kt++){
            short8 bf = *(const short8*)(inb + ((16*rt+lc)*KSTR + 32*kt + 8*lg)*2);
            d = __builtin_amdgcn_mfma_f32_16x16x32_bf16(aw[kt], bf, d, 0,0,0);
        }
        float o0 = d[0]+bb[0], o1 = d[1]+bb[1], o2 = d[2]+bb[2], o3 = d[3]+bb[3];
        if (ACT){ o0=lrelu(o0); o1=lrelu(o1); o2=lrelu(o2); o3=lrelu(o3); }
        uint2 u; u.x = cvtpk(o0,o1); u.y = cvtpk(o2,o3);
        *(uint2*)(outb + ((16*rt+lc)*136 + 16*wv + 4*lg)*2) = u;
    }
}

// ---------------- synth5: fused, LDS=34816 (4 blocks/CU, exact 1 round), barrier-free layer3 ----
// LDS: phase A: abA [0,8704) | abB [8704,17408) (pe aliased). After h1: whole [0,34816) = w2.
__global__ __launch_bounds__(512, 4) void synth5(
    const float* __restrict__ pos_b1, const float* __restrict__ pos_b2,
    const float* __restrict__ pos_b3, const float* __restrict__ sk_b2,
    const float* __restrict__ ws, float* __restrict__ out)
{
    __shared__ __align__(16) unsigned char lds[34816];
    unsigned char* abA = lds;
    unsigned char* abB = lds + 8704;
    unsigned char* PEb = abB;

    const int tid = threadIdx.x;
    const int wv = tid >> 6, lane = tid & 63, lg = lane >> 4, lc = lane & 15;
    const int t0 = blockIdx.x * 32;
    const unsigned short* wg16 = (const unsigned short*)((const char*)ws + WSBF_BYTE);
    const f32x4 z = {0.f,0.f,0.f,0.f};

    // ---- phase 0: build pe into LDS ----
    for (int i = tid; i < 1152; i += 512){
        int r = i/36, j0 = (i - r*36)*2;
        float pf = (float)(-1.0 + 2.0*(double)(t0+r)/32767.0);
        float v0 = pe_val(pf, j0);
        float v1 = pe_val(pf, j0+1);
        *(unsigned*)(PEb + (r*72 + j0)*2) = cvtpk(v0, v1);
    }
    __syncthreads();

    // ---- phase A: pos-MLP + A1, weights as global A-frags (no staging) ----
    layerGg<2,72,true>  (wg16+OP1, PEb, abA, pos_b1, wv, lg, lc);   // g1
    __syncthreads();
    layerGg<4,136,true> (wg16+OP2, abA, abB, pos_b2, wv, lg, lc);   // g2
    __syncthreads();
    layerGg<4,136,false>(wg16+OP3, abB, abA, pos_b3, wv, lg, lc);   // P
    __syncthreads();
    layerGg<4,136,false>(wg16+OS1, abA, abB, nullptr, wv, lg, lc);  // A1
    __syncthreads();

    // ---- h1 fragments (wave's own 32 rows) from abB + c1 ----
    short8 hf[2][4];
    {
        const int b = lc & 7;
        const float* c1g = ws + WS_C1 + b*128;
        #pragma unroll
        for (int rtl=0;rtl<2;rtl++){
            int tl = 4*wv + 2*rtl + (lc>>3);
            #pragma unroll
            for (int kt=0;kt<4;kt++){
                short8 a1v = *(const short8*)(abB + (tl*136 + 32*kt + 8*lg)*2);
                const float* cp = c1g + 32*kt + 8*lg;
                f32x4 c0 = *(const f32x4*)cp;
                f32x4 c1v = *(const f32x4*)(cp+4);
                float h[8];
                #pragma unroll
                for (int e=0;e<4;e++){
                    h[e]   = lrelu(bf2f(a1v[e])   + c0[e]);
                    h[4+e] = lrelu(bf2f(a1v[4+e]) + c1v[e]);
                }
                uint4 t4; t4.x=cvtpk(h[0],h[1]); t4.y=cvtpk(h[2],h[3]);
                t4.z=cvtpk(h[4],h[5]); t4.w=cvtpk(h[6],h[7]);
                hf[rtl][kt] = __builtin_bit_cast(short8, t4);
            }
        }
    }
    __syncthreads();   // all h1 LDS reads done; phase-A LDS dead

    // ---- stage w2 over the whole LDS; drain once ----
    {
        const unsigned char* src = (const unsigned char*)(wg16 + OS2);
        for (int c = wv; c < 34; c += 8)
            __builtin_amdgcn_global_load_lds(
                (const __attribute__((address_space(1))) unsigned int*)(src + (c<<10) + lane*16),
                (__attribute__((address_space(3))) unsigned int*)(lds + (c<<10)), 16, 0, 0);
    }
    VMCNT0; __syncthreads();

    // ---- layer2 (swapped, w2 from LDS) + in-register transpose to layer3 B-fragments ----
    short8 h2B[2][4];
    {
        const int sA = (2*(lg&1))*16 + lc;
        const int sB = sA + 16;
        const bool hi = (lg>>1) != 0;
        #pragma unroll
        for (int kt2=0; kt2<4; kt2++){
            unsigned dpk[2][2][2];
            #pragma unroll
            for (int p=0;p<2;p++){
                int n2t = 2*kt2+p;
                short8 aw[4];
                #pragma unroll
                for (int kt=0;kt<4;kt++)
                    aw[kt] = *(const short8*)(lds + ((16*n2t+lc)*136 + 32*kt + 8*lg)*2);
                f32x4 b2 = *(const f32x4*)(sk_b2 + 16*n2t + 4*lg);
                #pragma unroll
                for (int rtl=0;rtl<2;rtl++){
                    f32x4 d = z;
                    #pragma unroll
                    for (int kt=0;kt<4;kt++)
                        d = __builtin_amdgcn_mfma_f32_16x16x32_bf16(aw[kt], hf[rtl][kt], d, 0,0,0);
                    float o0=lrelu(d[0]+b2[0]), o1=lrelu(d[1]+b2[1]);
                    float o2=lrelu(d[2]+b2[2]), o3=lrelu(d[3]+b2[3]);
                    dpk[p][rtl][0] = cvtpk(o0,o1);
                    dpk[p][rtl][1] = cvtpk(o2,o3);
                }
            }
            #pragma unroll
            for (int rtl=0;rtl<2;rtl++){
                unsigned a0 = (unsigned)__shfl((int)dpk[0][rtl][0], sA, 64);
                unsigned b0 = (unsigned)__shfl((int)dpk[1][rtl][0], sA, 64);
                unsigned a1 = (unsigned)__shfl((int)dpk[0][rtl][1], sA, 64);
                unsigned b1 = (unsigned)__shfl((int)dpk[1][rtl][1], sA, 64);
                unsigned a2 = (unsigned)__shfl((int)dpk[0][rtl][0], sB, 64);
                unsigned b2u= (unsigned)__shfl((int)dpk[1][rtl][0], sB, 64);
                unsigned a3 = (unsigned)__shfl((int)dpk[0][rtl][1], sB, 64);
                unsigned b3u= (unsigned)__shfl((int)dpk[1][rtl][1], sB, 64);
                uint4 uu;
                uu.x = hi ? b0 : a0;  uu.y = hi ? b1 : a1;
                uu.z = hi ? b2u : a2; uu.w = hi ? b3u : a3;
                h2B[rtl][kt2] = __builtin_bit_cast(short8, uu);
            }
        }
    }
    // no barrier: from here each wave is fully independent (no LDS use)

    // ---- layer3 (swapped): w3 A-frags streamed from global (L2-resident), fused exp/sel ----
    float SSa[2][4], WWa[2][4];
    #pragma unroll
    for (int r=0;r<2;r++)
        #pragma unroll
        for (int q=0;q<4;q++){ SSa[r][q]=0.f; WWa[r][q]=0.f; }

    const unsigned short* w3g = wg16 + OS3;
    const float* selg = ws + WS_SEL + (lc & 7)*512;
    const float* b3g  = ws + WS_B3P;
    #pragma unroll 1
    for (int c=0;c<8;c++){
        #pragma unroll
        for (int nl=0;nl<4;nl++){
            int n3t = 4*c + nl;
            short8 bw[4];
            #pragma unroll
            for (int kt=0;kt<4;kt++)
                bw[kt] = *(const short8*)(w3g + (64*c + 16*nl + lc)*136 + 32*kt + 8*lg);
            f32x4 d3[2]; d3[0]=z; d3[1]=z;
            #pragma unroll
            for (int rtl=0;rtl<2;rtl++){
                #pragma unroll
                for (int kt=0;kt<4;kt++)
                    d3[rtl] = __builtin_amdgcn_mfma_f32_16x16x32_bf16(bw[kt], h2B[rtl][kt], d3[rtl], 0,0,0);
            }
            f32x4 b3 = *(const f32x4*)(b3g + 16*n3t + 4*lg);
            f32x4 sv = *(const f32x4*)(selg + 16*n3t + 4*lg);
            #pragma unroll
            for (int rtl=0;rtl<2;rtl++){
                #pragma unroll
                for (int q=0;q<4;q++){
                    float e = exp2fast(fmaf(d3[rtl][q], LOG2E, b3[q]));
                    SSa[rtl][q] += e;
                    WWa[rtl][q] = fmaf(e, sv[q], WWa[rtl][q]);
                }
            }
        }
    }

    // ---- epilogue: reduce over lg, env interp, write ----
    #pragma unroll
    for (int rtl=0;rtl<2;rtl++){
        float s = SSa[rtl][0]+SSa[rtl][1]+SSa[rtl][2]+SSa[rtl][3];
        float w = WWa[rtl][0]+WWa[rtl][1]+WWa[rtl][2]+WWa[rtl][3];
        s += __shfl_xor(s, 16, 64); s += __shfl_xor(s, 32, 64);
        w += __shfl_xor(w, 16, 64); w += __shfl_xor(w, 32, 64);
        if (lg == 0){
            int tl = 4*wv + 2*rtl + (lc>>3);
            int b  = lc & 7;
            int t  = t0 + tl;
            float coord = (t + 0.5f)*(1.0f/256.0f) - 0.5f;
            float fi = floorf(coord); float frac = coord - fi;
            int i0 = (int)fi; int i1 = i0 + 1;
            i0 = min(max(i0,0),NFRM-1); i1 = min(max(i1,0),NFRM-1);
            float e0 = ws[WS_ENV8 + b*NFRM + i0], e1 = ws[WS_ENV8 + b*NFRM + i1];
            float envv = e0*(1.0f-frac) + e1*frac;
            out[b*T_SAMP + t] = (w/s) * envv * ws[WS_VAL+b];
        }
    }
}

extern "C" void kernel_launch(void* const* d_in, const int* in_sizes, int n_in,
                              void* d_out, int out_size, void* d_ws, size_t ws_size,
                              hipStream_t stream)
{
    (void)in_sizes; (void)n_in; (void)out_size;
    const float* x       = (const float*)d_in[0];
    const float* wt      = (const float*)d_in[1];
    const float* tc_w1   = (const float*)d_in[2];
    const float* tc_b1   = (const float*)d_in[3];
    const float* tc_w2   = (const float*)d_in[4];
    const float* tc_b2   = (const float*)d_in[5];
    const float* tc_w3   = (const float*)d_in[6];
    const float* tc_b3   = (const float*)d_in[7];
    const float* env_w1  = (const float*)d_in[8];
    const float* env_b1  = (const float*)d_in[9];
    const float* env_w2  = (const float*)d_in[10];
    const float* env_b2  = (const float*)d_in[11];
    const float* env_w3  = (const float*)d_in[12];
    const float* env_b3  = (const float*)d_in[13];
    const float* pos_w1  = (const float*)d_in[14];
    const float* pos_b1  = (const float*)d_in[15];
    const float* pos_w2  = (const float*)d_in[16];
    const float* pos_b2  = (const float*)d_in[17];
    const float* pos_w3  = (const float*)d_in[18];
    const float* pos_b3  = (const float*)d_in[19];
    const float* sk_w1   = (const float*)d_in[20];
    const float* sk_b1   = (const float*)d_in[21];
    const float* sk_w2   = (const float*)d_in[22];
    const float* sk_b2   = (const float*)d_in[23];
    const float* sk_w3   = (const float*)d_in[24];
    const float* sk_b3   = (const float*)d_in[25];
    float* ws  = (float*)d_ws;
    float* out = (float*)d_out;

    if (ws_size < (size_t)WS_NEED) return;  // ws proven >= WS_NEED on this harness

    hipLaunchKernelGGL(setup_kernel, dim3(1 + (WTOT+255)/256), dim3(256), 0, stream,
        x, wt, tc_w1, tc_b1, tc_w2, tc_b2, tc_w3, tc_b3,
        env_w1, env_b1, env_w2, env_b2, env_w3, env_b3,
        sk_w1, sk_b1, pos_w1, pos_w2, pos_w3, sk_w2, sk_w3, sk_b3, ws);

    hipLaunchKernelGGL(synth5, dim3(T_SAMP/32), dim3(512), 0, stream,
        pos_b1, pos_b2, pos_b3, sk_b2, ws, out);
}

// Round 9
// 104.226 us; speedup vs baseline: 1.2156x; 1.2156x over previous
//
#include <hip/hip_runtime.h>
#include <math.h>

#define D 128
#define B 8
#define T_SAMP 32768
#define K 512
#define NT 8
#define NFRM 128

// ws float-region layout
#define WS_C1   0
#define WS_ENV8 1024
#define WS_SEL  2048
#define WS_VAL  6144
#define WS_B3P  6160
// bf16 transposed-weight region (byte offset; element offsets below)
#define WSBF_BYTE 32768
#define OP1 0        // pw1T [128][72]
#define OP2 9216     // pw2T [128][136]
#define OP3 26624    // pw3T
#define OS1 44032    // skw1T
#define OS2 61440    // skw2T
#define OS3 78848    // skw3T [512][136]
#define WTOT 148480
#define WS_NEED (WSBF_BYTE + WTOT*2)

typedef __attribute__((ext_vector_type(8))) short short8;
typedef __attribute__((ext_vector_type(4))) float f32x4;

#define LOG2E 1.4426950408889634f

__device__ __forceinline__ float lrelu(float v){ return fmaxf(v, 0.2f*v); }

__device__ __forceinline__ unsigned cvtpk(float lo, float hi){
    unsigned r;
    asm("v_cvt_pk_bf16_f32 %0, %1, %2" : "=v"(r) : "v"(lo), "v"(hi));
    return r;
}
__device__ __forceinline__ unsigned short bfr(float f){
    unsigned u = __builtin_bit_cast(unsigned, f); u += 0x7fffu + ((u>>16)&1u);
    return (unsigned short)(u>>16);
}
__device__ __forceinline__ float bf2f(short s){
    unsigned u = ((unsigned)(unsigned short)s) << 16;
    return __builtin_bit_cast(float, u);
}
__device__ __forceinline__ float exp2fast(float x){
#if __has_builtin(__builtin_amdgcn_exp2f)
    return __builtin_amdgcn_exp2f(x);
#else
    return __expf(x*0.6931471805599453f);
#endif
}
__device__ __forceinline__ float sin_rev(float fr){
#if __has_builtin(__builtin_amdgcn_sinf)
    return __builtin_amdgcn_sinf(fr);
#else
    return __sinf(fr*6.283185307179586f);
#endif
}
__device__ __forceinline__ float cos_rev(float fr){
#if __has_builtin(__builtin_amdgcn_cosf)
    return __builtin_amdgcn_cosf(fr);
#else
    return __cosf(fr*6.283185307179586f);
#endif
}
// pe value for column j (0=raw pos, 1..16 sin, 17..32 cos, else 0)
__device__ __forceinline__ float pe_val(float pf, int j){
    if (j == 0) return pf;
    if (j > 32) return 0.f;
    const bool is_sin = (j <= 16);
    int e = is_sin ? (j + 125) : (j + 109);     // 2^(j-2) or 2^(j-18): revolutions scale
    float sc = __builtin_bit_cast(float, ((unsigned)e) << 23);
    float u = pf * sc;
    float fr = u - floorf(u);
    return is_sin ? sin_rev(fr) : cos_rev(fr);
}

#define VMCNT0 asm volatile("s_waitcnt vmcnt(0)" ::: "memory")

// ---------------- prep helper (fp32, tiny) ----------------
__device__ void layer128(const float* __restrict__ in, const float* __restrict__ w,
                         const float* __restrict__ bias, float* __restrict__ outp,
                         int tid, int mode)
{
    int n = tid & 127, bg = tid >> 7;
    const float* i0 = in + (bg*4+0)*D;
    const float* i1 = in + (bg*4+1)*D;
    const float* i2 = in + (bg*4+2)*D;
    const float* i3 = in + (bg*4+3)*D;
    float bb = bias[n];
    float a0=bb,a1=bb,a2=bb,a3=bb;
    for (int j=0;j<D;j++){
        float wv = w[j*D+n];
        a0 = fmaf(i0[j], wv, a0);
        a1 = fmaf(i1[j], wv, a1);
        a2 = fmaf(i2[j], wv, a2);
        a3 = fmaf(i3[j], wv, a3);
    }
    if (mode==0){ a0=lrelu(a0);a1=lrelu(a1);a2=lrelu(a2);a3=lrelu(a3); }
    else if (mode==1){ a0=fabsf(a0);a1=fabsf(a1);a2=fabsf(a2);a3=fabsf(a3); }
    outp[(bg*4+0)*D+n]=a0;
    outp[(bg*4+1)*D+n]=a1;
    outp[(bg*4+2)*D+n]=a2;
    outp[(bg*4+3)*D+n]=a3;
}

// block 0: prep (c1/env/sel/values/b3p). blocks 1..: transpose weights to bf16 k-contig padded.
__global__ __launch_bounds__(256) void setup_kernel(
    const float* __restrict__ x, const float* __restrict__ wt,
    const float* __restrict__ tc_w1, const float* __restrict__ tc_b1,
    const float* __restrict__ tc_w2, const float* __restrict__ tc_b2,
    const float* __restrict__ tc_w3, const float* __restrict__ tc_b3,
    const float* __restrict__ env_w1, const float* __restrict__ env_b1,
    const float* __restrict__ env_w2, const float* __restrict__ env_b2,
    const float* __restrict__ env_w3, const float* __restrict__ env_b3,
    const float* __restrict__ sk_w1, const float* __restrict__ sk_b1,
    const float* __restrict__ pos_w1, const float* __restrict__ pos_w2,
    const float* __restrict__ pos_w3, const float* __restrict__ sk_w2,
    const float* __restrict__ sk_w3, const float* __restrict__ sk_b3,
    float* __restrict__ ws)
{
    __shared__ float xl[B*D], buf1[B*D], buf2[B*D];
    __shared__ float lgts[B*NT], pmax[NT*8], mxr[NT];
    __shared__ int idxl[B];
    int tid = threadIdx.x;

    if (blockIdx.x != 0){
        int idx = (blockIdx.x - 1)*256 + tid;
        if (idx >= WTOT) return;
        unsigned short* wb = (unsigned short*)((char*)ws + WSBF_BYTE);
        float v;
        if (idx < OP2){
            int n = idx/72, k = idx%72;
            v = (k < 33) ? pos_w1[k*D + n] : 0.f;
        } else if (idx < OS3){
            int r = idx - OP2; int wsel = r/17408; int i = r%17408;
            int n = i/136, k = i%136;
            const float* W = wsel==0?pos_w2: wsel==1?pos_w3: wsel==2? sk_w1 : sk_w2;
            v = (k < 128) ? W[k*D + n] : 0.f;
        } else {
            int i = idx - OS3; int n = i/136, k = i%136;
            v = (k < 128) ? sk_w3[k*K + n] : 0.f;
        }
        wb[idx] = bfr(v);
        return;
    }

    for (int i=tid;i<B*D;i+=256) xl[i]=x[i];
    for (int i=tid;i<K;i+=256) ws[WS_B3P+i] = sk_b3[i]*LOG2E;
    __syncthreads();
    layer128(xl, tc_w1, tc_b1, buf1, tid, 0);
    __syncthreads();
    layer128(buf1, tc_w2, tc_b2, buf2, tid, 0);
    __syncthreads();
    if (tid < 64){
        int b = tid>>3, n = tid&7;
        float a = tc_b3[n];
        for (int j=0;j<D;j++) a = fmaf(buf2[b*D+j], tc_w3[j*NT+n], a);
        lgts[b*NT+n] = a;
    } else if (tid < 128){
        int r = (tid-64)>>3, p = tid&7;
        float m = -1e30f;
        for (int k=p*64;k<p*64+64;k++) m = fmaxf(m, wt[r*K+k]);
        pmax[r*8+p] = m;
    }
    __syncthreads();
    if (tid < 8){
        int b = tid; float m = -1e30f; int idx = 0;
        for (int n=0;n<NT;n++){ float v = lgts[b*NT+n]; if (v > m){ m=v; idx=n; } }
        float S = 0.f;
        for (int n=0;n<NT;n++) S += expf(lgts[b*NT+n]-m);
        ws[WS_VAL+b] = 1.0f/S;
        idxl[b] = idx;
    } else if (tid < 16){
        int r = tid-8; float m = -1e30f;
        for (int p=0;p<8;p++) m = fmaxf(m, pmax[r*8+p]);
        mxr[r] = m;
    }
    __syncthreads();
    for (int o=tid;o<B*K;o+=256){
        int b = o>>9, k = o&(K-1);
        int id = idxl[b];
        ws[WS_SEL+o] = wt[id*K+k] / (mxr[id] + 1e-8f);
    }
    layer128(xl, env_w1, env_b1, buf1, tid, 0);
    __syncthreads();
    layer128(buf1, env_w2, env_b2, buf2, tid, 0);
    __syncthreads();
    layer128(buf2, env_w3, env_b3, ws+WS_ENV8, tid, 1);
    layer128(xl, sk_w1, sk_b1, ws+WS_C1, tid, 2);
}

// swapped small layer: A-frags preloaded from GLOBAL; B-frags from LDS; out to LDS.
template<int NKT, int KSTR, bool ACT>
__device__ __forceinline__ void layerF(const short8* aw,
                                       const unsigned char* inb, unsigned char* outb,
                                       const float* biasp, int wv, int lg, int lc)
{
    const f32x4 z = {0.f,0.f,0.f,0.f};
    f32x4 bb = z;
    if (biasp) bb = *(const f32x4*)(biasp + 16*wv + 4*lg);
    #pragma unroll
    for (int rt=0;rt<2;rt++){
        f32x4 d = z;
        #pragma unroll
        for (int kt=0;kt<NKT;kt++){
            short8 bf = *(const short8*)(inb + ((16*rt+lc)*KSTR + 32*kt + 8*lg)*2);
            d = __builtin_amdgcn_mfma_f32_16x16x32_bf16(aw[kt], bf, d, 0,0,0);
        }
        float o0 = d[0]+bb[0], o1 = d[1]+bb[1], o2 = d[2]+bb[2], o3 = d[3]+bb[3];
        if (ACT){ o0=lrelu(o0); o1=lrelu(o1); o2=lrelu(o2); o3=lrelu(o3); }
        uint2 u; u.x = cvtpk(o0,o1); u.y = cvtpk(o2,o3);
        *(uint2*)(outb + ((16*rt+lc)*136 + 16*wv + 4*lg)*2) = u;
    }
}

// ---------------- synth6: fused; phase-A weights = prefetched global frags;
// LDS = 34816 (4 blocks/CU, exact 1 round). abA/abB live inside the w2 region.
// Layout: abA = lds+0 (8704), abB = lds+9216 (8704, pe aliased). After h1: lds = w2 (34816),
// then l3 dbuf slots [0,17408)/[17408,34816).
__global__ __launch_bounds__(512, 4) void synth6(
    const float* __restrict__ pos_b1, const float* __restrict__ pos_b2,
    const float* __restrict__ pos_b3, const float* __restrict__ sk_b2,
    const float* __restrict__ ws, float* __restrict__ out)
{
    __shared__ __align__(16) unsigned char lds[34816];
    unsigned char* abA = lds;
    unsigned char* abB = lds + 9216;
    unsigned char* PEb = abB;

    const int tid = threadIdx.x;
    const int wv = tid >> 6, lane = tid & 63, lg = lane >> 4, lc = lane & 15;
    const int t0 = blockIdx.x * 32;
    const unsigned short* wg16 = (const unsigned short*)((const char*)ws + WSBF_BYTE);
    const f32x4 z = {0.f,0.f,0.f,0.f};

    // ---- prefetch g1 A-frags + build pe into LDS ----
    short8 aw1[2];
    #pragma unroll
    for (int kt=0;kt<2;kt++)
        aw1[kt] = *(const short8*)(wg16 + OP1 + (16*wv+lc)*72 + 32*kt + 8*lg);
    for (int i = tid; i < 1152; i += 512){
        int r = i/36, j0 = (i - r*36)*2;
        float pf = (float)(-1.0 + 2.0*(double)(t0+r)/32767.0);
        float v0 = pe_val(pf, j0);
        float v1 = pe_val(pf, j0+1);
        *(unsigned*)(PEb + (r*72 + j0)*2) = cvtpk(v0, v1);
    }
    __syncthreads();

    // ---- g1 (issue g2 frags first so they fly under g1's MFMAs) ----
    short8 awn[4];
    #pragma unroll
    for (int kt=0;kt<4;kt++)
        awn[kt] = *(const short8*)(wg16 + OP2 + (16*wv+lc)*136 + 32*kt + 8*lg);
    layerF<2,72,true>(aw1, PEb, abA, pos_b1, wv, lg, lc);      // g1: pe -> abA
    __syncthreads();

    // ---- g2 (issue P frags) ----
    {
        short8 awp[4];
        #pragma unroll
        for (int kt=0;kt<4;kt++)
            awp[kt] = *(const short8*)(wg16 + OP3 + (16*wv+lc)*136 + 32*kt + 8*lg);
        layerF<4,136,true>(awn, abA, abB, pos_b2, wv, lg, lc); // g2: abA -> abB
        #pragma unroll
        for (int kt=0;kt<4;kt++) awn[kt] = awp[kt];
    }
    __syncthreads();

    // ---- P (issue A1 frags) ----
    {
        short8 awp[4];
        #pragma unroll
        for (int kt=0;kt<4;kt++)
            awp[kt] = *(const short8*)(wg16 + OS1 + (16*wv+lc)*136 + 32*kt + 8*lg);
        layerF<4,136,false>(awn, abB, abA, pos_b3, wv, lg, lc); // P: abB -> abA
        #pragma unroll
        for (int kt=0;kt<4;kt++) awn[kt] = awp[kt];
    }
    __syncthreads();

    // ---- A1 ----
    layerF<4,136,false>(awn, abA, abB, nullptr, wv, lg, lc);    // A1: abA -> abB
    __syncthreads();

    // ---- stage w2 part 1 (chunks avoiding abB = bytes 9216..18432 -> chunks 9..17) ----
    {
        const unsigned char* src = (const unsigned char*)(wg16 + OS2);
        for (int c = wv; c < 34; c += 8)
            if (c < 9 || c >= 18)
                __builtin_amdgcn_global_load_lds(
                    (const __attribute__((address_space(1))) unsigned int*)(src + (c<<10) + lane*16),
                    (__attribute__((address_space(3))) unsigned int*)(lds + (c<<10)), 16, 0, 0);
    }

    // ---- h1 fragments (wave's own 32 rows) from abB + c1 ----
    short8 hf[2][4];
    {
        const int b = lc & 7;
        const float* c1g = ws + WS_C1 + b*128;
        #pragma unroll
        for (int rtl=0;rtl<2;rtl++){
            int tl = 4*wv + 2*rtl + (lc>>3);
            #pragma unroll
            for (int kt=0;kt<4;kt++){
                short8 a1v = *(const short8*)(abB + (tl*136 + 32*kt + 8*lg)*2);
                const float* cp = c1g + 32*kt + 8*lg;
                f32x4 c0 = *(const f32x4*)cp;
                f32x4 c1v = *(const f32x4*)(cp+4);
                float h[8];
                #pragma unroll
                for (int e=0;e<4;e++){
                    h[e]   = lrelu(bf2f(a1v[e])   + c0[e]);
                    h[4+e] = lrelu(bf2f(a1v[4+e]) + c1v[e]);
                }
                uint4 t4; t4.x=cvtpk(h[0],h[1]); t4.y=cvtpk(h[2],h[3]);
                t4.z=cvtpk(h[4],h[5]); t4.w=cvtpk(h[6],h[7]);
                hf[rtl][kt] = __builtin_bit_cast(short8, t4);
            }
        }
    }
    __syncthreads();   // abB reads done

    // ---- stage w2 part 2 (chunks 9..17 over dead abB), drain all ----
    {
        const unsigned char* src = (const unsigned char*)(wg16 + OS2);
        for (int c = 9 + wv; c < 18; c += 8)
            __builtin_amdgcn_global_load_lds(
                (const __attribute__((address_space(1))) unsigned int*)(src + (c<<10) + lane*16),
                (__attribute__((address_space(3))) unsigned int*)(lds + (c<<10)), 16, 0, 0);
    }
    VMCNT0; __syncthreads();

    // ---- layer2 (swapped, w2 from LDS) + in-register transpose to layer3 B-fragments ----
    short8 h2B[2][4];
    {
        const int sA = (2*(lg&1))*16 + lc;
        const int sB = sA + 16;
        const bool hi = (lg>>1) != 0;
        __builtin_amdgcn_s_setprio(1);
        #pragma unroll
        for (int kt2=0; kt2<4; kt2++){
            unsigned dpk[2][2][2];
            #pragma unroll
            for (int p=0;p<2;p++){
                int n2t = 2*kt2+p;
                short8 aw[4];
                #pragma unroll
                for (int kt=0;kt<4;kt++)
                    aw[kt] = *(const short8*)(lds + ((16*n2t+lc)*136 + 32*kt + 8*lg)*2);
                f32x4 b2 = *(const f32x4*)(sk_b2 + 16*n2t + 4*lg);
                #pragma unroll
                for (int rtl=0;rtl<2;rtl++){
                    f32x4 d = z;
                    #pragma unroll
                    for (int kt=0;kt<4;kt++)
                        d = __builtin_amdgcn_mfma_f32_16x16x32_bf16(aw[kt], hf[rtl][kt], d, 0,0,0);
                    float o0=lrelu(d[0]+b2[0]), o1=lrelu(d[1]+b2[1]);
                    float o2=lrelu(d[2]+b2[2]), o3=lrelu(d[3]+b2[3]);
                    dpk[p][rtl][0] = cvtpk(o0,o1);
                    dpk[p][rtl][1] = cvtpk(o2,o3);
                }
            }
            #pragma unroll
            for (int rtl=0;rtl<2;rtl++){
                unsigned a0 = (unsigned)__shfl((int)dpk[0][rtl][0], sA, 64);
                unsigned b0 = (unsigned)__shfl((int)dpk[1][rtl][0], sA, 64);
                unsigned a1 = (unsigned)__shfl((int)dpk[0][rtl][1], sA, 64);
                unsigned b1 = (unsigned)__shfl((int)dpk[1][rtl][1], sA, 64);
                unsigned a2 = (unsigned)__shfl((int)dpk[0][rtl][0], sB, 64);
                unsigned b2u= (unsigned)__shfl((int)dpk[1][rtl][0], sB, 64);
                unsigned a3 = (unsigned)__shfl((int)dpk[0][rtl][1], sB, 64);
                unsigned b3u= (unsigned)__shfl((int)dpk[1][rtl][1], sB, 64);
                uint4 uu;
                uu.x = hi ? b0 : a0;  uu.y = hi ? b1 : a1;
                uu.z = hi ? b2u : a2; uu.w = hi ? b3u : a3;
                h2B[rtl][kt2] = __builtin_bit_cast(short8, uu);
            }
        }
        __builtin_amdgcn_s_setprio(0);
    }
    __syncthreads();   // all w2 reads done; LDS free for w3 dbuf

    // ---- layer3 (swapped) over 8 w3 col-chunks (dbuf 2x17408), fused exp/sel accumulate ----
    float SSa[2][4], WWa[2][4];
    #pragma unroll
    for (int r=0;r<2;r++)
        #pragma unroll
        for (int q=0;q<4;q++){ SSa[r][q]=0.f; WWa[r][q]=0.f; }

    auto stage = [&](int elemoff, unsigned char* dst, int nchunks){
        const unsigned char* src = (const unsigned char*)(wg16 + elemoff);
        for (int c = wv; c < nchunks; c += 8)
            __builtin_amdgcn_global_load_lds(
                (const __attribute__((address_space(1))) unsigned int*)(src + (c<<10) + lane*16),
                (__attribute__((address_space(3))) unsigned int*)(dst + (c<<10)), 16, 0, 0);
    };

    stage(OS3, lds, 17); VMCNT0; __syncthreads();
    const float* selg = ws + WS_SEL + (lc & 7)*512;
    const float* b3g  = ws + WS_B3P;
    for (int c=0;c<8;c++){
        const unsigned char* slot = lds + (c&1)*17408;
        if (c < 7) stage(OS3 + (c+1)*8704, lds + ((c+1)&1)*17408, 17);
        __builtin_amdgcn_s_setprio(1);
        #pragma unroll
        for (int nl=0;nl<4;nl++){
            int n3t = 4*c + nl;
            short8 bw[4];
            #pragma unroll
            for (int kt=0;kt<4;kt++)
                bw[kt] = *(const short8*)(slot + ((16*nl+lc)*136 + 32*kt + 8*lg)*2);
            f32x4 d3[2]; d3[0]=z; d3[1]=z;
            #pragma unroll
            for (int rtl=0;rtl<2;rtl++){
                #pragma unroll
                for (int kt=0;kt<4;kt++)
                    d3[rtl] = __builtin_amdgcn_mfma_f32_16x16x32_bf16(bw[kt], h2B[rtl][kt], d3[rtl], 0,0,0);
            }
            f32x4 b3 = *(const f32x4*)(b3g + 16*n3t + 4*lg);
            f32x4 sv = *(const f32x4*)(selg + 16*n3t + 4*lg);
            #pragma unroll
            for (int rtl=0;rtl<2;rtl++){
                #pragma unroll
                for (int q=0;q<4;q++){
                    float e = exp2fast(fmaf(d3[rtl][q], LOG2E, b3[q]));
                    SSa[rtl][q] += e;
                    WWa[rtl][q] = fmaf(e, sv[q], WWa[rtl][q]);
                }
            }
        }
        __builtin_amdgcn_s_setprio(0);
        VMCNT0; __syncthreads();
    }

    // ---- epilogue: reduce over lg, env interp, write ----
    #pragma unroll
    for (int rtl=0;rtl<2;rtl++){
        float s = SSa[rtl][0]+SSa[rtl][1]+SSa[rtl][2]+SSa[rtl][3];
        float w = WWa[rtl][0]+WWa[rtl][1]+WWa[rtl][2]+WWa[rtl][3];
        s += __shfl_xor(s, 16, 64); s += __shfl_xor(s, 32, 64);
        w += __shfl_xor(w, 16, 64); w += __shfl_xor(w, 32, 64);
        if (lg == 0){
            int tl = 4*wv + 2*rtl + (lc>>3);
            int b  = lc & 7;
            int t  = t0 + tl;
            float coord = (t + 0.5f)*(1.0f/256.0f) - 0.5f;
            float fi = floorf(coord); float frac = coord - fi;
            int i0 = (int)fi; int i1 = i0 + 1;
            i0 = min(max(i0,0),NFRM-1); i1 = min(max(i1,0),NFRM-1);
            float e0 = ws[WS_ENV8 + b*NFRM + i0], e1 = ws[WS_ENV8 + b*NFRM + i1];
            float envv = e0*(1.0f-frac) + e1*frac;
            out[b*T_SAMP + t] = (w/s) * envv * ws[WS_VAL+b];
        }
    }
}

extern "C" void kernel_launch(void* const* d_in, const int* in_sizes, int n_in,
                              void* d_out, int out_size, void* d_ws, size_t ws_size,
                              hipStream_t stream)
{
    (void)in_sizes; (void)n_in; (void)out_size;
    const float* x       = (const float*)d_in[0];
    const float* wt      = (const float*)d_in[1];
    const float* tc_w1   = (const float*)d_in[2];
    const float* tc_b1   = (const float*)d_in[3];
    const float* tc_w2   = (const float*)d_in[4];
    const float* tc_b2   = (const float*)d_in[5];
    const float* tc_w3   = (const float*)d_in[6];
    const float* tc_b3   = (const float*)d_in[7];
    const float* env_w1  = (const float*)d_in[8];
    const float* env_b1  = (const float*)d_in[9];
    const float* env_w2  = (const float*)d_in[10];
    const float* env_b2  = (const float*)d_in[11];
    const float* env_w3  = (const float*)d_in[12];
    const float* env_b3  = (const float*)d_in[13];
    const float* pos_w1  = (const float*)d_in[14];
    const float* pos_b1  = (const float*)d_in[15];
    const float* pos_w2  = (const float*)d_in[16];
    const float* pos_b2  = (const float*)d_in[17];
    const float* pos_w3  = (const float*)d_in[18];
    const float* pos_b3  = (const float*)d_in[19];
    const float* sk_w1   = (const float*)d_in[20];
    const float* sk_b1   = (const float*)d_in[21];
    const float* sk_w2   = (const float*)d_in[22];
    const float* sk_b2   = (const float*)d_in[23];
    const float* sk_w3   = (const float*)d_in[24];
    const float* sk_b3   = (const float*)d_in[25];
    float* ws  = (float*)d_ws;
    float* out = (float*)d_out;

    if (ws_size < (size_t)WS_NEED) return;  // ws proven >= WS_NEED on this harness

    hipLaunchKernelGGL(setup_kernel, dim3(1 + (WTOT+255)/256), dim3(256), 0, stream,
        x, wt, tc_w1, tc_b1, tc_w2, tc_b2, tc_w3, tc_b3,
        env_w1, env_b1, env_w2, env_b2, env_w3, env_b3,
        sk_w1, sk_b1, pos_w1, pos_w2, pos_w3, sk_w2, sk_w3, sk_b3, ws);

    hipLaunchKernelGGL(synth6, dim3(T_SAMP/32), dim3(512), 0, stream,
        pos_b1, pos_b2, pos_b3, sk_b2, ws, out);
}

// Round 10
// 92.026 us; speedup vs baseline: 1.3768x; 1.1326x over previous
//
#include <hip/hip_runtime.h>
#include <math.h>

#define D 128
#define B 8
#define T_SAMP 32768
#define K 512
#define NT 8
#define NFRM 128

// ws float-region layout
#define WS_C1   0
#define WS_ENV8 1024
#define WS_SEL  2048
#define WS_VAL  6144
#define WS_B3P  6160
// bf16 fragment-interleaved weight region. Frag (nt,kt) = 512 contiguous elements;
// element (lane,e) holds W[k=32kt+8*(lane>>4)+e][n=16nt+(lane&15)].
#define WSBF_BYTE 32768
#define FP1 0        // pw1 : 8nt x 2kt x 512  (k>=33 zero-padded)
#define FP2 8192     // pw2 : 8nt x 4kt x 512
#define FP3 24576    // pw3
#define FS1 40960    // skw1
#define FS2 57344    // skw2
#define FS3 73728    // skw3: 32nt x 4kt x 512
#define WTOT 139264
#define WS_NEED (WSBF_BYTE + WTOT*2)

typedef __attribute__((ext_vector_type(8))) short short8;
typedef __attribute__((ext_vector_type(4))) float f32x4;

#define LOG2E 1.4426950408889634f

__device__ __forceinline__ float lrelu(float v){ return fmaxf(v, 0.2f*v); }

__device__ __forceinline__ unsigned cvtpk(float lo, float hi){
    unsigned r;
    asm("v_cvt_pk_bf16_f32 %0, %1, %2" : "=v"(r) : "v"(lo), "v"(hi));
    return r;
}
__device__ __forceinline__ unsigned short bfr(float f){
    unsigned u = __builtin_bit_cast(unsigned, f); u += 0x7fffu + ((u>>16)&1u);
    return (unsigned short)(u>>16);
}
__device__ __forceinline__ float bf2f(short s){
    unsigned u = ((unsigned)(unsigned short)s) << 16;
    return __builtin_bit_cast(float, u);
}
__device__ __forceinline__ float exp2fast(float x){
#if __has_builtin(__builtin_amdgcn_exp2f)
    return __builtin_amdgcn_exp2f(x);
#else
    return __expf(x*0.6931471805599453f);
#endif
}
__device__ __forceinline__ float sin_rev(float fr){
#if __has_builtin(__builtin_amdgcn_sinf)
    return __builtin_amdgcn_sinf(fr);
#else
    return __sinf(fr*6.283185307179586f);
#endif
}
__device__ __forceinline__ float cos_rev(float fr){
#if __has_builtin(__builtin_amdgcn_cosf)
    return __builtin_amdgcn_cosf(fr);
#else
    return __cosf(fr*6.283185307179586f);
#endif
}
__device__ __forceinline__ float pe_val(float pf, int j){
    if (j == 0) return pf;
    if (j > 32) return 0.f;
    const bool is_sin = (j <= 16);
    int e = is_sin ? (j + 125) : (j + 109);
    float sc = __builtin_bit_cast(float, ((unsigned)e) << 23);
    float u = pf * sc;
    float fr = u - floorf(u);
    return is_sin ? sin_rev(fr) : cos_rev(fr);
}

#define VMCNT0 asm volatile("s_waitcnt vmcnt(0)" ::: "memory")

// ---------------- prep helper (fp32, tiny) ----------------
__device__ void layer128(const float* __restrict__ in, const float* __restrict__ w,
                         const float* __restrict__ bias, float* __restrict__ outp,
                         int tid, int mode)
{
    int n = tid & 127, bg = tid >> 7;
    const float* i0 = in + (bg*4+0)*D;
    const float* i1 = in + (bg*4+1)*D;
    const float* i2 = in + (bg*4+2)*D;
    const float* i3 = in + (bg*4+3)*D;
    float bb = bias[n];
    float a0=bb,a1=bb,a2=bb,a3=bb;
    #pragma unroll 4
    for (int j=0;j<D;j++){
        float wv = w[j*D+n];
        a0 = fmaf(i0[j], wv, a0);
        a1 = fmaf(i1[j], wv, a1);
        a2 = fmaf(i2[j], wv, a2);
        a3 = fmaf(i3[j], wv, a3);
    }
    if (mode==0){ a0=lrelu(a0);a1=lrelu(a1);a2=lrelu(a2);a3=lrelu(a3); }
    else if (mode==1){ a0=fabsf(a0);a1=fabsf(a1);a2=fabsf(a2);a3=fabsf(a3); }
    outp[(bg*4+0)*D+n]=a0;
    outp[(bg*4+1)*D+n]=a1;
    outp[(bg*4+2)*D+n]=a2;
    outp[(bg*4+3)*D+n]=a3;
}

// block 0: tc chain + values + sel. block 1: env chain + c1 + b3p.
// blocks 2..: fragment-interleaved bf16 weight transpose.
__global__ __launch_bounds__(256) void setup_kernel(
    const float* __restrict__ x, const float* __restrict__ wt,
    const float* __restrict__ tc_w1, const float* __restrict__ tc_b1,
    const float* __restrict__ tc_w2, const float* __restrict__ tc_b2,
    const float* __restrict__ tc_w3, const float* __restrict__ tc_b3,
    const float* __restrict__ env_w1, const float* __restrict__ env_b1,
    const float* __restrict__ env_w2, const float* __restrict__ env_b2,
    const float* __restrict__ env_w3, const float* __restrict__ env_b3,
    const float* __restrict__ sk_w1, const float* __restrict__ sk_b1,
    const float* __restrict__ pos_w1, const float* __restrict__ pos_w2,
    const float* __restrict__ pos_w3, const float* __restrict__ sk_w2,
    const float* __restrict__ sk_w3, const float* __restrict__ sk_b3,
    float* __restrict__ ws)
{
    __shared__ float xl[B*D], buf1[B*D], buf2[B*D];
    __shared__ float lgts[B*NT], pmax[NT*8], mxr[NT];
    __shared__ int idxl[B];
    int tid = threadIdx.x;

    if (blockIdx.x >= 2){
        int idx = (blockIdx.x - 2)*256 + tid;
        if (idx >= WTOT) return;
        unsigned short* wb = (unsigned short*)((char*)ws + WSBF_BYTE);
        int r; const float* Wp; int ncols = D; int nkt = 4; bool p1 = false;
        if (idx < FP2){ r = idx - FP1; Wp = pos_w1; nkt = 2; p1 = true; }
        else if (idx < FP3){ r = idx - FP2; Wp = pos_w2; }
        else if (idx < FS1){ r = idx - FP3; Wp = pos_w3; }
        else if (idx < FS2){ r = idx - FS1; Wp = sk_w1; }
        else if (idx < FS3){ r = idx - FS2; Wp = sk_w2; }
        else { r = idx - FS3; Wp = sk_w3; ncols = K; }
        int frag = r >> 9, lane = (r >> 3) & 63, e = r & 7;
        int nt2 = frag / nkt, kt = frag - nt2*nkt;
        int k = 32*kt + 8*(lane>>4) + e;
        int n = 16*nt2 + (lane&15);
        float v = (p1 && k >= 33) ? 0.f : Wp[k*ncols + n];
        wb[idx] = bfr(v);
        return;
    }

    for (int i=tid;i<B*D;i+=256) xl[i]=x[i];
    __syncthreads();

    if (blockIdx.x == 1){
        for (int i=tid;i<K;i+=256) ws[WS_B3P+i] = sk_b3[i]*LOG2E;
        layer128(xl, env_w1, env_b1, buf1, tid, 0);
        __syncthreads();
        layer128(buf1, env_w2, env_b2, buf2, tid, 0);
        __syncthreads();
        layer128(buf2, env_w3, env_b3, ws+WS_ENV8, tid, 1);
        layer128(xl, sk_w1, sk_b1, ws+WS_C1, tid, 2);
        return;
    }

    // block 0: tc chain + wavetable prep
    layer128(xl, tc_w1, tc_b1, buf1, tid, 0);
    __syncthreads();
    layer128(buf1, tc_w2, tc_b2, buf2, tid, 0);
    __syncthreads();
    if (tid < 64){
        int b = tid>>3, n = tid&7;
        float a = tc_b3[n];
        #pragma unroll 4
        for (int j=0;j<D;j++) a = fmaf(buf2[b*D+j], tc_w3[j*NT+n], a);
        lgts[b*NT+n] = a;
    } else if (tid < 128){
        int r = (tid-64)>>3, p = tid&7;
        float m = -1e30f;
        for (int k=p*64;k<p*64+64;k++) m = fmaxf(m, wt[r*K+k]);
        pmax[r*8+p] = m;
    }
    __syncthreads();
    if (tid < 8){
        int b = tid; float m = -1e30f; int idx = 0;
        for (int n=0;n<NT;n++){ float v = lgts[b*NT+n]; if (v > m){ m=v; idx=n; } }
        float S = 0.f;
        for (int n=0;n<NT;n++) S += expf(lgts[b*NT+n]-m);
        ws[WS_VAL+b] = 1.0f/S;
        idxl[b] = idx;
    } else if (tid < 16){
        int r = tid-8; float m = -1e30f;
        for (int p=0;p<8;p++) m = fmaxf(m, pmax[r*8+p]);
        mxr[r] = m;
    }
    __syncthreads();
    for (int o=tid;o<B*K;o+=256){
        int b = o>>9, k = o&(K-1);
        int id = idxl[b];
        ws[WS_SEL+o] = wt[id*K+k] / (mxr[id] + 1e-8f);
    }
}

// swapped small layer: A-frags preloaded from GLOBAL (frag-interleaved, coalesced);
// B-frags linear from LDS; output written in next layer's B-frag layout.
template<int NKT_IN, bool ACT>
__device__ __forceinline__ void layerF(const short8* aw,
                                       const unsigned char* inb, unsigned char* outb,
                                       const float* biasp, int wv, int lg, int lc)
{
    const f32x4 z = {0.f,0.f,0.f,0.f};
    const int lane16 = (lg*16 + lc)*16;
    // out position: frag (rt, wv>>1), lane' = (2*(wv&1)+(lg>>1))*16+lc, e-start 4*(lg&1)
    const int obase = ((wv>>1)<<10) + (((2*(wv&1) + (lg>>1))*16 + lc)<<4) + ((lg&1)<<3);
    f32x4 bb = z;
    if (biasp) bb = *(const f32x4*)(biasp + 16*wv + 4*lg);
    #pragma unroll
    for (int rt=0;rt<2;rt++){
        f32x4 d = z;
        #pragma unroll
        for (int kt=0;kt<NKT_IN;kt++){
            short8 bf = *(const short8*)(inb + ((rt*NKT_IN+kt)<<10) + lane16);
            d = __builtin_amdgcn_mfma_f32_16x16x32_bf16(aw[kt], bf, d, 0,0,0);
        }
        float o0 = d[0]+bb[0], o1 = d[1]+bb[1], o2 = d[2]+bb[2], o3 = d[3]+bb[3];
        if (ACT){ o0=lrelu(o0); o1=lrelu(o1); o2=lrelu(o2); o3=lrelu(o3); }
        uint2 u; u.x = cvtpk(o0,o1); u.y = cvtpk(o2,o3);
        *(uint2*)(outb + (rt<<12) + obase) = u;
    }
}

// ---------------- synth7: fragment-interleaved everything; LDS=32768 ----------------
// LDS: phase A: abA [0,8192) | abB [8192,16384) (pe = abB front 4KB).
// After h1: whole 32768 = w2 (32 frag-KB); l3 dbuf slots 2 x 16384.
__global__ __launch_bounds__(512, 4) void synth7(
    const float* __restrict__ pos_b1, const float* __restrict__ pos_b2,
    const float* __restrict__ pos_b3, const float* __restrict__ sk_b2,
    const float* __restrict__ ws, float* __restrict__ out)
{
    __shared__ __align__(16) unsigned char lds[32768];
    unsigned char* abA = lds;
    unsigned char* abB = lds + 8192;
    unsigned char* PEb = abB;

    const int tid = threadIdx.x;
    const int wv = tid >> 6, lane = tid & 63, lg = lane >> 4, lc = lane & 15;
    const int lane16 = lane*16;
    const int t0 = blockIdx.x * 32;
    const unsigned short* wg16 = (const unsigned short*)((const char*)ws + WSBF_BYTE);
    const f32x4 z = {0.f,0.f,0.f,0.f};

    auto stage = [&](int elemoff, unsigned char* dst, int nchunks){
        const unsigned char* src = (const unsigned char*)(wg16 + elemoff);
        for (int c = wv; c < nchunks; c += 8)
            __builtin_amdgcn_global_load_lds(
                (const __attribute__((address_space(1))) unsigned int*)(src + (c<<10) + lane16),
                (__attribute__((address_space(3))) unsigned int*)(dst + (c<<10)), 16, 0, 0);
    };

    // ---- prefetch g1 A-frags (coalesced) + build pe (frag-interleaved) ----
    short8 aw1[2];
    #pragma unroll
    for (int kt=0;kt<2;kt++)
        aw1[kt] = *(const short8*)(wg16 + FP1 + ((wv*2+kt)<<9) + lane*8);
    for (int i = tid; i < 1024; i += 512){
        int r = i >> 5, p = i & 31;
        int j0 = 2*p;
        float pf = (float)(-1.0 + 2.0*(double)(t0+r)/32767.0);
        float v0 = pe_val(pf, j0);
        float v1 = pe_val(pf, j0+1);
        int kt = j0 >> 5, rem = j0 & 31;
        int by = (((r>>4)*2 + kt)<<10) + (((rem>>3)*16 + (r&15))<<4) + (rem&7)*2;
        *(unsigned*)(PEb + by) = cvtpk(v0, v1);
    }
    __syncthreads();

    // ---- phase A: issue next layer's frags before current MFMAs ----
    short8 awn[4];
    #pragma unroll
    for (int kt=0;kt<4;kt++)
        awn[kt] = *(const short8*)(wg16 + FP2 + ((wv*4+kt)<<9) + lane*8);
    layerF<2,true>(aw1, PEb, abA, pos_b1, wv, lg, lc);          // g1: pe -> abA
    __syncthreads();
    {
        short8 awp[4];
        #pragma unroll
        for (int kt=0;kt<4;kt++)
            awp[kt] = *(const short8*)(wg16 + FP3 + ((wv*4+kt)<<9) + lane*8);
        layerF<4,true>(awn, abA, abB, pos_b2, wv, lg, lc);      // g2: abA -> abB
        #pragma unroll
        for (int kt=0;kt<4;kt++) awn[kt] = awp[kt];
    }
    __syncthreads();
    {
        short8 awp[4];
        #pragma unroll
        for (int kt=0;kt<4;kt++)
            awp[kt] = *(const short8*)(wg16 + FS1 + ((wv*4+kt)<<9) + lane*8);
        layerF<4,false>(awn, abB, abA, pos_b3, wv, lg, lc);     // P: abB -> abA
        #pragma unroll
        for (int kt=0;kt<4;kt++) awn[kt] = awp[kt];
    }
    __syncthreads();
    layerF<4,false>(awn, abA, abB, nullptr, wv, lg, lc);        // A1: abA -> abB
    __syncthreads();

    // ---- stage w2 first 8KB over dead abA; h1 frags from abB + c1 ----
    stage(FS2, lds, 8);
    short8 hf[2][4];
    {
        const int b = lc & 7;
        const float* c1g = ws + WS_C1 + b*128;
        #pragma unroll
        for (int rtl=0;rtl<2;rtl++){
            int tl = 4*wv + 2*rtl + (lc>>3);
            int fr = tl >> 4, lrow = tl & 15;
            #pragma unroll
            for (int kt=0;kt<4;kt++){
                short8 a1v = *(const short8*)(abB + ((fr*4+kt)<<10) + ((lg*16+lrow)<<4));
                const float* cp = c1g + 32*kt + 8*lg;
                f32x4 c0 = *(const f32x4*)cp;
                f32x4 c1v = *(const f32x4*)(cp+4);
                float h[8];
                #pragma unroll
                for (int e=0;e<4;e++){
                    h[e]   = lrelu(bf2f(a1v[e])   + c0[e]);
                    h[4+e] = lrelu(bf2f(a1v[4+e]) + c1v[e]);
                }
                uint4 t4; t4.x=cvtpk(h[0],h[1]); t4.y=cvtpk(h[2],h[3]);
                t4.z=cvtpk(h[4],h[5]); t4.w=cvtpk(h[6],h[7]);
                hf[rtl][kt] = __builtin_bit_cast(short8, t4);
            }
        }
    }
    __syncthreads();   // abB reads done

    // ---- stage w2 rest (24KB over dead abB + tail), drain ----
    {
        const unsigned char* src = (const unsigned char*)(wg16 + FS2);
        for (int c = 8 + wv; c < 32; c += 8)
            __builtin_amdgcn_global_load_lds(
                (const __attribute__((address_space(1))) unsigned int*)(src + (c<<10) + lane16),
                (__attribute__((address_space(3))) unsigned int*)(lds + (c<<10)), 16, 0, 0);
    }
    VMCNT0; __syncthreads();

    // ---- layer2 (swapped, w2 frags linear from LDS) + in-register transpose ----
    short8 h2B[2][4];
    {
        const int sA = (2*(lg&1))*16 + lc;
        const int sB = sA + 16;
        const bool hi = (lg>>1) != 0;
        __builtin_amdgcn_s_setprio(1);
        #pragma unroll
        for (int kt2=0; kt2<4; kt2++){
            unsigned dpk[2][2][2];
            #pragma unroll
            for (int p=0;p<2;p++){
                int n2t = 2*kt2+p;
                short8 aw[4];
                #pragma unroll
                for (int kt=0;kt<4;kt++)
                    aw[kt] = *(const short8*)(lds + ((n2t*4+kt)<<10) + lane16);
                f32x4 b2 = *(const f32x4*)(sk_b2 + 16*n2t + 4*lg);
                #pragma unroll
                for (int rtl=0;rtl<2;rtl++){
                    f32x4 d = z;
                    #pragma unroll
                    for (int kt=0;kt<4;kt++)
                        d = __builtin_amdgcn_mfma_f32_16x16x32_bf16(aw[kt], hf[rtl][kt], d, 0,0,0);
                    float o0=lrelu(d[0]+b2[0]), o1=lrelu(d[1]+b2[1]);
                    float o2=lrelu(d[2]+b2[2]), o3=lrelu(d[3]+b2[3]);
                    dpk[p][rtl][0] = cvtpk(o0,o1);
                    dpk[p][rtl][1] = cvtpk(o2,o3);
                }
            }
            #pragma unroll
            for (int rtl=0;rtl<2;rtl++){
                unsigned a0 = (unsigned)__shfl((int)dpk[0][rtl][0], sA, 64);
                unsigned b0 = (unsigned)__shfl((int)dpk[1][rtl][0], sA, 64);
                unsigned a1 = (unsigned)__shfl((int)dpk[0][rtl][1], sA, 64);
                unsigned b1 = (unsigned)__shfl((int)dpk[1][rtl][1], sA, 64);
                unsigned a2 = (unsigned)__shfl((int)dpk[0][rtl][0], sB, 64);
                unsigned b2u= (unsigned)__shfl((int)dpk[1][rtl][0], sB, 64);
                unsigned a3 = (unsigned)__shfl((int)dpk[0][rtl][1], sB, 64);
                unsigned b3u= (unsigned)__shfl((int)dpk[1][rtl][1], sB, 64);
                uint4 uu;
                uu.x = hi ? b0 : a0;  uu.y = hi ? b1 : a1;
                uu.z = hi ? b2u : a2; uu.w = hi ? b3u : a3;
                h2B[rtl][kt2] = __builtin_bit_cast(short8, uu);
            }
        }
        __builtin_amdgcn_s_setprio(0);
    }
    __syncthreads();   // w2 reads done; LDS free for w3 dbuf

    // ---- layer3 (swapped) over 8 w3 16KB chunks (dbuf), fused exp/sel, q-summed ----
    float SSa[2], WWa[2];
    SSa[0]=0.f; SSa[1]=0.f; WWa[0]=0.f; WWa[1]=0.f;

    stage(FS3, lds, 16); VMCNT0; __syncthreads();
    const float* selg = ws + WS_SEL + (lc & 7)*512;
    const float* b3g  = ws + WS_B3P;
    for (int c=0;c<8;c++){
        const unsigned char* slot = lds + (c&1)*16384;
        if (c < 7) stage(FS3 + (c+1)*8192, lds + ((c+1)&1)*16384, 16);
        __builtin_amdgcn_s_setprio(1);
        #pragma unroll
        for (int nl=0;nl<4;nl++){
            int n3t = 4*c + nl;
            short8 bw[4];
            #pragma unroll
            for (int kt=0;kt<4;kt++)
                bw[kt] = *(const short8*)(slot + ((nl*4+kt)<<10) + lane16);
            f32x4 d3[2]; d3[0]=z; d3[1]=z;
            #pragma unroll
            for (int rtl=0;rtl<2;rtl++){
                #pragma unroll
                for (int kt=0;kt<4;kt++)
                    d3[rtl] = __builtin_amdgcn_mfma_f32_16x16x32_bf16(bw[kt], h2B[rtl][kt], d3[rtl], 0,0,0);
            }
            f32x4 b3 = *(const f32x4*)(b3g + 16*n3t + 4*lg);
            f32x4 sv = *(const f32x4*)(selg + 16*n3t + 4*lg);
            #pragma unroll
            for (int rtl=0;rtl<2;rtl++){
                float e0 = exp2fast(fmaf(d3[rtl][0], LOG2E, b3[0]));
                float e1 = exp2fast(fmaf(d3[rtl][1], LOG2E, b3[1]));
                float e2 = exp2fast(fmaf(d3[rtl][2], LOG2E, b3[2]));
                float e3 = exp2fast(fmaf(d3[rtl][3], LOG2E, b3[3]));
                SSa[rtl] += (e0+e1) + (e2+e3);
                float w = fmaf(e0, sv[0], fmaf(e1, sv[1], fmaf(e2, sv[2], e3*sv[3])));
                WWa[rtl] += w;
            }
        }
        __builtin_amdgcn_s_setprio(0);
        VMCNT0; __syncthreads();
    }

    // ---- epilogue: reduce over lg, env interp, write ----
    #pragma unroll
    for (int rtl=0;rtl<2;rtl++){
        float s = SSa[rtl];
        float w = WWa[rtl];
        s += __shfl_xor(s, 16, 64); s += __shfl_xor(s, 32, 64);
        w += __shfl_xor(w, 16, 64); w += __shfl_xor(w, 32, 64);
        if (lg == 0){
            int tl = 4*wv + 2*rtl + (lc>>3);
            int b  = lc & 7;
            int t  = t0 + tl;
            float coord = (t + 0.5f)*(1.0f/256.0f) - 0.5f;
            float fi = floorf(coord); float frac = coord - fi;
            int i0 = (int)fi; int i1 = i0 + 1;
            i0 = min(max(i0,0),NFRM-1); i1 = min(max(i1,0),NFRM-1);
            float e0 = ws[WS_ENV8 + b*NFRM + i0], e1 = ws[WS_ENV8 + b*NFRM + i1];
            float envv = e0*(1.0f-frac) + e1*frac;
            out[b*T_SAMP + t] = (w/s) * envv * ws[WS_VAL+b];
        }
    }
}

extern "C" void kernel_launch(void* const* d_in, const int* in_sizes, int n_in,
                              void* d_out, int out_size, void* d_ws, size_t ws_size,
                              hipStream_t stream)
{
    (void)in_sizes; (void)n_in; (void)out_size;
    const float* x       = (const float*)d_in[0];
    const float* wt      = (const float*)d_in[1];
    const float* tc_w1   = (const float*)d_in[2];
    const float* tc_b1   = (const float*)d_in[3];
    const float* tc_w2   = (const float*)d_in[4];
    const float* tc_b2   = (const float*)d_in[5];
    const float* tc_w3   = (const float*)d_in[6];
    const float* tc_b3   = (const float*)d_in[7];
    const float* env_w1  = (const float*)d_in[8];
    const float* env_b1  = (const float*)d_in[9];
    const float* env_w2  = (const float*)d_in[10];
    const float* env_b2  = (const float*)d_in[11];
    const float* env_w3  = (const float*)d_in[12];
    const float* env_b3  = (const float*)d_in[13];
    const float* pos_w1  = (const float*)d_in[14];
    const float* pos_b1  = (const float*)d_in[15];
    const float* pos_w2  = (const float*)d_in[16];
    const float* pos_b2  = (const float*)d_in[17];
    const float* pos_w3  = (const float*)d_in[18];
    const float* pos_b3  = (const float*)d_in[19];
    const float* sk_w1   = (const float*)d_in[20];
    const float* sk_b1   = (const float*)d_in[21];
    const float* sk_w2   = (const float*)d_in[22];
    const float* sk_b2   = (const float*)d_in[23];
    const float* sk_w3   = (const float*)d_in[24];
    const float* sk_b3   = (const float*)d_in[25];
    float* ws  = (float*)d_ws;
    float* out = (float*)d_out;

    if (ws_size < (size_t)WS_NEED) return;  // ws proven >= WS_NEED on this harness

    hipLaunchKernelGGL(setup_kernel, dim3(2 + (WTOT+255)/256), dim3(256), 0, stream,
        x, wt, tc_w1, tc_b1, tc_w2, tc_b2, tc_w3, tc_b3,
        env_w1, env_b1, env_w2, env_b2, env_w3, env_b3,
        sk_w1, sk_b1, pos_w1, pos_w2, pos_w3, sk_w2, sk_w3, sk_b3, ws);

    hipLaunchKernelGGL(synth7, dim3(T_SAMP/32), dim3(512), 0, stream,
        pos_b1, pos_b2, pos_b3, sk_b2, ws, out);
}